// Round 1
// 406.579 us; speedup vs baseline: 1.0100x; 1.0100x over previous
//
#include <hip/hip_runtime.h>

// EvidentialGNN: 2-layer GCN. evidence = softplus(gcn2(relu(gcn1(x)))).
// Outputs concatenated: (evidence[50000,64], h[50000,256]).
// R8: (a) fp32->bf16 cast of x fused into GEMM1 A-staging (cast kernel deleted,
//     -153MB traffic, -1 launch); (b) GEMM epilogues write dinv[row]-prescaled
//     rows, so both agg kernels drop the per-edge dinv gather chain (~850k
//     random 4B dependent loads) and use pure adds.

#define N_NODES 50000
#define IN_DIM 512
#define HID 256
#define NCLS 64

typedef unsigned short u16;
typedef unsigned int u32;
typedef __attribute__((ext_vector_type(8))) short short8;
typedef __attribute__((ext_vector_type(4))) float float4_t;

__device__ __forceinline__ float bf_lo(u32 v) {
    u32 u = v << 16; float f; __builtin_memcpy(&f, &u, 4); return f;
}
__device__ __forceinline__ float bf_hi(u32 v) {
    u32 u = v & 0xffff0000u; float f; __builtin_memcpy(&f, &u, 4); return f;
}
__device__ __forceinline__ u16 f2bf(float f) {   // RNE float->bf16
    u32 u; __builtin_memcpy(&u, &f, 4);
    return (u16)((u + 0x7fffu + ((u >> 16) & 1u)) >> 16);
}
__device__ __forceinline__ void add8(float* acc, uint4 v) {
    acc[0] += bf_lo(v.x); acc[1] += bf_hi(v.x);
    acc[2] += bf_lo(v.y); acc[3] += bf_hi(v.y);
    acc[4] += bf_lo(v.z); acc[5] += bf_hi(v.z);
    acc[6] += bf_lo(v.w); acc[7] += bf_hi(v.w);
}
__device__ __forceinline__ void acc8(float* acc, uint4 v, float w) {
    acc[0] += w * bf_lo(v.x); acc[1] += w * bf_hi(v.x);
    acc[2] += w * bf_lo(v.y); acc[3] += w * bf_hi(v.y);
    acc[4] += w * bf_lo(v.z); acc[5] += w * bf_hi(v.z);
    acc[6] += w * bf_lo(v.w); acc[7] += w * bf_hi(v.w);
}

// ---------------- graph prep ----------------
__global__ void init_kernel(int* __restrict__ cnt, int* __restrict__ cursor, int n) {
    int i = blockIdx.x * blockDim.x + threadIdx.x;
    if (i < n) { cnt[i] = 0; cursor[i] = 0; }
}

__global__ void count_kernel(const int* __restrict__ dst, int* __restrict__ cnt, int E) {
    int e = blockIdx.x * blockDim.x + threadIdx.x;
    if (e < E) atomicAdd(&cnt[dst[e]], 1);
}

// s1: per-block reduce of cnt -> blocksum; fused dinv = rsqrt(cnt+1).
__global__ __launch_bounds__(256) void s1_kernel(const int* __restrict__ cnt,
                                                 int* __restrict__ blocksum,
                                                 float* __restrict__ dinv, int n) {
    int tid = threadIdx.x;
    int i = blockIdx.x * 256 + tid;
    int c = (i < n) ? cnt[i] : 0;
    if (i < n) dinv[i] = rsqrtf((float)(c + 1));  // +1 self-loop
    __shared__ int s[256];
    s[tid] = c;
    __syncthreads();
    for (int off = 128; off > 0; off >>= 1) {
        if (tid < off) s[tid] += s[tid + off];
        __syncthreads();
    }
    if (tid == 0) blocksum[blockIdx.x] = s[0];
}

// s3 (fused s2): every block scans the <=256 block sums in LDS to get its own
// offset, then does the block-local exclusive scan -> row_ptr[0..n].
__global__ __launch_bounds__(256) void s3_kernel(const int* __restrict__ cnt,
                                                 const int* __restrict__ blocksum,
                                                 int* __restrict__ row_ptr, int n, int nb) {
    __shared__ int bs[256];
    __shared__ int s[256];
    int tid = threadIdx.x;
    int v = (tid < nb) ? blocksum[tid] : 0;
    bs[tid] = v;
    __syncthreads();
    for (int off = 1; off < 256; off <<= 1) {
        int a = (tid >= off) ? bs[tid - off] : 0;
        __syncthreads();
        bs[tid] += a;
        __syncthreads();
    }
    int boff = (blockIdx.x == 0) ? 0 : bs[blockIdx.x - 1];
    int i = blockIdx.x * 256 + tid;
    int c = (i < n) ? cnt[i] : 0;
    s[tid] = c;
    __syncthreads();
    for (int off = 1; off < 256; off <<= 1) {
        int a = (tid >= off) ? s[tid - off] : 0;
        __syncthreads();
        s[tid] += a;
        __syncthreads();
    }
    if (i <= n) row_ptr[i] = boff + s[tid] - c;
}

__global__ void fill_kernel(const int* __restrict__ src, const int* __restrict__ dst,
                            const int* __restrict__ row_ptr, int* __restrict__ cursor,
                            int* __restrict__ csr_src, int E) {
    int e = blockIdx.x * blockDim.x + threadIdx.x;
    if (e >= E) return;
    int d = dst[e];
    int pos = row_ptr[d] + atomicAdd(&cursor[d], 1);
    csr_src[pos] = src[e];
}

// ---------------- casts ----------------
// Wt[n][k] = bf16(W[k][n]);  W is [K,N] row-major, Wt is [N,K] row-major.
__global__ __launch_bounds__(256) void tcast_kernel(const float* __restrict__ W,
                                                    u16* __restrict__ Wt, int K, int N) {
    int idx = blockIdx.x * 256 + threadIdx.x;
    if (idx >= K * N) return;
    int n = idx / K, k = idx - n * K;
    Wt[idx] = f2bf(W[k * N + n]);
}

// ---------------- bf16 MFMA GEMM ----------------
// C[M,N] = A[M,K] @ Bt[N,K]^T, fp32 accumulate, bf16 out.
// AF32: A is fp32, converted to bf16 in the A-staging (reg-stage + ds_write).
// SCALE: epilogue multiplies each output row by rowscale[row] (= dinv).
// 256 threads = 4 waves; per-wave 64x64 via 4x4 of 16x16x32 MFMA. BK=32.
template <int BM, int BN, int K, int N, bool AF32, bool SCALE>
__global__ __launch_bounds__(256) void mfma_gemm_kernel(const void* __restrict__ Ain,
                                                        const u16* __restrict__ Bt,
                                                        u16* __restrict__ C, int M,
                                                        const float* __restrict__ rowscale) {
    constexpr int WCOLS = (BN >= 128) ? 2 : 1;
    constexpr int WROWS = 4 / WCOLS;
    static_assert(WROWS * 64 == BM && WCOLS * 64 == BN, "wave tiling mismatch");
    constexpr int LDSA = BM * 32;
    __shared__ u16 lds[LDSA + BN * 32];

    const int tid = threadIdx.x;
    const int wave = tid >> 6, lane = tid & 63;
    const int wm = wave / WCOLS, wn = wave % WCOLS;
    const int quad = lane >> 4, l15 = lane & 15;
    const int row0 = blockIdx.y * BM;
    const int col0 = blockIdx.x * BN;

    float4_t acc[4][4];
#pragma unroll
    for (int mi = 0; mi < 4; mi++)
#pragma unroll
        for (int ni = 0; ni < 4; ni++) {
            float4_t z = {0.f, 0.f, 0.f, 0.f};
            acc[mi][ni] = z;
        }

    for (int k0 = 0; k0 < K; k0 += 32) {
#pragma unroll
        for (int i = 0; i < BM / 64; i++) {
            int c = tid + i * 256;
            int r = c >> 2;
            int gr = row0 + r;
            gr = gr < M ? gr : M - 1;
            if constexpr (AF32) {
                const float* gp = (const float*)Ain + (long)gr * K + k0 + (c & 3) * 8;
                float4 p0 = ((const float4*)gp)[0];
                float4 p1 = ((const float4*)gp)[1];
                uint4 o;
                o.x = (u32)f2bf(p0.x) | ((u32)f2bf(p0.y) << 16);
                o.y = (u32)f2bf(p0.z) | ((u32)f2bf(p0.w) << 16);
                o.z = (u32)f2bf(p1.x) | ((u32)f2bf(p1.y) << 16);
                o.w = (u32)f2bf(p1.z) | ((u32)f2bf(p1.w) << 16);
                *(uint4*)(lds + c * 8) = o;
            } else {
                const u16* gp = (const u16*)Ain + (long)gr * K + k0 + (c & 3) * 8;
                u16* lp = lds + c * 8;
                __builtin_amdgcn_global_load_lds((const __attribute__((address_space(1))) u32*)gp,
                                                 (__attribute__((address_space(3))) u32*)lp,
                                                 16, 0, 0);
            }
        }
#pragma unroll
        for (int i = 0; i < BN / 64; i++) {
            int c = tid + i * 256;
            int r = c >> 2;
            const u16* gp = Bt + (long)(col0 + r) * K + k0 + (c & 3) * 8;
            u16* lp = lds + LDSA + c * 8;
            __builtin_amdgcn_global_load_lds((const __attribute__((address_space(1))) u32*)gp,
                                             (__attribute__((address_space(3))) u32*)lp,
                                             16, 0, 0);
        }
        __syncthreads();

        short8 af[4], bfr[4];
#pragma unroll
        for (int mi = 0; mi < 4; mi++)
            af[mi] = *(const short8*)(lds + (wm * 64 + mi * 16 + l15) * 32 + quad * 8);
#pragma unroll
        for (int ni = 0; ni < 4; ni++)
            bfr[ni] = *(const short8*)(lds + LDSA + (wn * 64 + ni * 16 + l15) * 32 + quad * 8);
#pragma unroll
        for (int mi = 0; mi < 4; mi++)
#pragma unroll
            for (int ni = 0; ni < 4; ni++)
                acc[mi][ni] = __builtin_amdgcn_mfma_f32_16x16x32_bf16(af[mi], bfr[ni],
                                                                      acc[mi][ni], 0, 0, 0);
        __syncthreads();
    }

#pragma unroll
    for (int mi = 0; mi < 4; mi++) {
#pragma unroll
        for (int r = 0; r < 4; r++) {
            int row = row0 + wm * 64 + mi * 16 + quad * 4 + r;
            if (row < M) {
                float sc = 1.f;
                if constexpr (SCALE) sc = rowscale[row];
#pragma unroll
                for (int ni = 0; ni < 4; ni++) {
                    int col = col0 + wn * 64 + ni * 16 + l15;
                    C[(long)row * N + col] = f2bf(acc[mi][ni][r] * sc);
                }
            }
        }
    }
}

// ---------------- agg1: wide rows (FEAT=256), one node per wave ----------------
// Rows in t are PRE-SCALED by dinv[src] (GEMM epilogue), so the inner loop is a
// pure row-sum: out = dinv[d]*(sum + self) + b.  32 lanes cover a 512B row with
// uint4; 2 edge groups; tiered unroll 16/8/2.
__global__ __launch_bounds__(256) void agg_wide_kernel(const u16* __restrict__ t,
                                                       const int* __restrict__ row_ptr,
                                                       const int* __restrict__ csr_src,
                                                       const float* __restrict__ dinv,
                                                       const float* __restrict__ bias,
                                                       float* __restrict__ out_f,
                                                       u16* __restrict__ out_bf, int n) {
    constexpr int FEAT = 256;
    int node = (blockIdx.x * blockDim.x + threadIdx.x) >> 6;
    int lane = threadIdx.x & 63;
    if (node >= n) return;
    const int g = lane >> 5;       // edge group 0..1
    const int r = lane & 31;       // lane within row
    float acc[8] = {};
    const int beg = row_ptr[node], end = row_ptr[node + 1];
    int e = beg;
    for (; e + 16 <= end; e += 16) {   // 8 edges per group, 16 chains in flight
        int s[8]; uint4 v[8];
#pragma unroll
        for (int u = 0; u < 8; u++) s[u] = csr_src[e + u * 2 + g];
#pragma unroll
        for (int u = 0; u < 8; u++) v[u] = *(const uint4*)(t + (long)s[u] * FEAT + r * 8);
#pragma unroll
        for (int u = 0; u < 8; u++) add8(acc, v[u]);
    }
    for (; e + 8 <= end; e += 8) {
        int s[4]; uint4 v[4];
#pragma unroll
        for (int u = 0; u < 4; u++) s[u] = csr_src[e + u * 2 + g];
#pragma unroll
        for (int u = 0; u < 4; u++) v[u] = *(const uint4*)(t + (long)s[u] * FEAT + r * 8);
#pragma unroll
        for (int u = 0; u < 4; u++) add8(acc, v[u]);
    }
    for (; e < end; e += 2) {
        int ee = e + g;
        if (ee < end) {
            int s = csr_src[ee];
            uint4 v = *(const uint4*)(t + (long)s * FEAT + r * 8);
            add8(acc, v);
        }
    }
#pragma unroll
    for (int j = 0; j < 8; j++) acc[j] += __shfl_xor(acc[j], 32, 64);

    if (lane < 32) {
        const float di = dinv[node];
        uint4 sv = *(const uint4*)(t + (long)node * FEAT + lane * 8);
        float self[8] = {bf_lo(sv.x), bf_hi(sv.x), bf_lo(sv.y), bf_hi(sv.y),
                         bf_lo(sv.z), bf_hi(sv.z), bf_lo(sv.w), bf_hi(sv.w)};
        float4 b0 = *(const float4*)(bias + lane * 8);
        float4 b1 = *(const float4*)(bias + lane * 8 + 4);
        float bb[8] = {b0.x, b0.y, b0.z, b0.w, b1.x, b1.y, b1.z, b1.w};
        float rv[8];
#pragma unroll
        for (int j = 0; j < 8; j++)
            rv[j] = fmaxf(di * (acc[j] + self[j]) + bb[j], 0.f);  // relu
        long base = (long)node * FEAT + lane * 8;
        *(float4*)(out_f + base) = make_float4(rv[0], rv[1], rv[2], rv[3]);
        *(float4*)(out_f + base + 4) = make_float4(rv[4], rv[5], rv[6], rv[7]);
        uint4 o;
        o.x = (u32)f2bf(rv[0]) | ((u32)f2bf(rv[1]) << 16);
        o.y = (u32)f2bf(rv[2]) | ((u32)f2bf(rv[3]) << 16);
        o.z = (u32)f2bf(rv[4]) | ((u32)f2bf(rv[5]) << 16);
        o.w = (u32)f2bf(rv[6]) | ((u32)f2bf(rv[7]) << 16);
        *(uint4*)(out_bf + base) = o;
    }
}

// ---------------- agg2: narrow rows (FEAT=64), 8 nodes per wave ----------------
// Rows in t are PRE-SCALED by dinv[src].  8 lanes x 16B cover a 128B row; each
// 8-lane group owns one node; 4 edges in flight per group (w=1/0 masks tails).
__global__ __launch_bounds__(256) void agg_n8_kernel(const u16* __restrict__ t,
                                                     const int* __restrict__ row_ptr,
                                                     const int* __restrict__ csr_src,
                                                     const float* __restrict__ dinv,
                                                     const float* __restrict__ bias,
                                                     float* __restrict__ out_f, int n) {
    constexpr int FEAT = 64;
    const int wid = (blockIdx.x * blockDim.x + threadIdx.x) >> 6;
    const int lane = threadIdx.x & 63;
    const int g = lane >> 3;   // node group 0..7
    const int r = lane & 7;    // lane within row
    const int node = wid * 8 + g;
    const bool valid = node < n;
    const int nd = valid ? node : (n - 1);
    const int beg = row_ptr[nd];
    const int deg = valid ? (row_ptr[nd + 1] - beg) : 0;
    float acc[8] = {};
    for (int e = 0;; e += 4) {
        if (!__any(e < deg)) break;
        int s[4]; float w[4]; uint4 v[4];
#pragma unroll
        for (int u = 0; u < 4; u++) {
            bool a = (e + u) < deg;
            s[u] = a ? csr_src[beg + e + u] : 0;
            w[u] = a ? 1.f : 0.f;
        }
#pragma unroll
        for (int u = 0; u < 4; u++) v[u] = *(const uint4*)(t + (long)s[u] * FEAT + r * 8);
#pragma unroll
        for (int u = 0; u < 4; u++) acc8(acc, v[u], w[u]);  // w=0 kills garbage rows
    }
    const float di = dinv[nd];
    uint4 sv = *(const uint4*)(t + (long)nd * FEAT + r * 8);
    float self[8] = {bf_lo(sv.x), bf_hi(sv.x), bf_lo(sv.y), bf_hi(sv.y),
                     bf_lo(sv.z), bf_hi(sv.z), bf_lo(sv.w), bf_hi(sv.w)};
    float4 b0 = *(const float4*)(bias + r * 8);
    float4 b1 = *(const float4*)(bias + r * 8 + 4);
    float bb[8] = {b0.x, b0.y, b0.z, b0.w, b1.x, b1.y, b1.z, b1.w};
    float rv[8];
#pragma unroll
    for (int j = 0; j < 8; j++) {
        float v = di * (acc[j] + self[j]) + bb[j];
        // fast softplus: max(v,0) + ln(1+exp(-|v|)) via v_exp/v_log
        rv[j] = fmaxf(v, 0.f) + __logf(1.f + __expf(-fabsf(v)));
    }
    if (valid) {
        long base = (long)nd * FEAT + r * 8;
        *(float4*)(out_f + base) = make_float4(rv[0], rv[1], rv[2], rv[3]);
        *(float4*)(out_f + base + 4) = make_float4(rv[4], rv[5], rv[6], rv[7]);
    }
}

extern "C" void kernel_launch(void* const* d_in, const int* in_sizes, int n_in,
                              void* d_out, int out_size, void* d_ws, size_t ws_size,
                              hipStream_t stream) {
    const float* x  = (const float*)d_in[0];
    const int*   ei = (const int*)d_in[1];
    const float* W1 = (const float*)d_in[2];
    const float* b1 = (const float*)d_in[3];
    const float* W2 = (const float*)d_in[4];
    const float* b2 = (const float*)d_in[5];

    float* evidence = (float*)d_out;                        // [50000, 64]
    float* h        = (float*)d_out + (long)N_NODES * NCLS; // [50000, 256]

    const int E = in_sizes[1] / 2;
    const int* src = ei;
    const int* dst = ei + E;

    const int NB = (N_NODES + 255) / 256;  // 196 scan blocks

    // workspace carve-up (16B-aligned regions)
    char* w = (char*)d_ws;
    int*   cnt      = (int*)w;  w += 50048 * 4;
    int*   cursor   = (int*)w;  w += 50048 * 4;
    int*   row_ptr  = (int*)w;  w += 50064 * 4;
    float* dinv     = (float*)w; w += 50048 * 4;
    int*   blocksum = (int*)w;  w += 256 * 4;
    int*   csr_src  = (int*)w;  w += 800000 * 4;
    u16*   hbf      = (u16*)w;  w += (long)N_NODES * IN_DIM * 2;  // h bf16 (only HID used)
    u16*   w1t      = (u16*)w;  w += IN_DIM * HID * 2;
    u16*   w2t      = (u16*)w;  w += HID * NCLS * 2;
    u16*   t1bf     = (u16*)w;  w += (long)N_NODES * HID * 2;     // reused as t2_bf
    u16*   t2bf     = t1bf;

    // graph prep
    init_kernel<<<NB, 256, 0, stream>>>(cnt, cursor, N_NODES);
    count_kernel<<<(E + 255) / 256, 256, 0, stream>>>(dst, cnt, E);
    s1_kernel<<<NB, 256, 0, stream>>>(cnt, blocksum, dinv, N_NODES);
    s3_kernel<<<NB, 256, 0, stream>>>(cnt, blocksum, row_ptr, N_NODES, NB);
    fill_kernel<<<(E + 255) / 256, 256, 0, stream>>>(src, dst, row_ptr, cursor, csr_src, E);

    // weight casts
    tcast_kernel<<<(IN_DIM * HID + 255) / 256, 256, 0, stream>>>(W1, w1t, IN_DIM, HID);
    tcast_kernel<<<(HID * NCLS + 255) / 256, 256, 0, stream>>>(W2, w2t, HID, NCLS);

    // layer 1: t1 = dinv .* (x @ W1)  (fp32 A fused-cast, scaled epilogue);
    //          h = relu(dinv[d]*(sum t1[s] + t1[d]) + b1), also h_bf
    {
        dim3 grid(HID / 128, (N_NODES + 127) / 128);
        mfma_gemm_kernel<128, 128, IN_DIM, HID, true, true>
            <<<grid, 256, 0, stream>>>(x, w1t, t1bf, N_NODES, dinv);
    }
    agg_wide_kernel<<<(N_NODES * 64 + 255) / 256, 256, 0, stream>>>(
        t1bf, row_ptr, csr_src, dinv, b1, h, hbf, N_NODES);

    // layer 2: t2 = dinv .* (h @ W2); evidence = softplus(dinv[d]*(sum+self) + b2)
    {
        dim3 grid(NCLS / 64, (N_NODES + 255) / 256);
        mfma_gemm_kernel<256, 64, HID, NCLS, false, true>
            <<<grid, 256, 0, stream>>>(hbf, w2t, t2bf, N_NODES, dinv);
    }
    {
        int waves = (N_NODES + 7) / 8;                 // 6250 waves
        int blocks = (waves + 3) / 4;                  // 4 waves per block
        agg_n8_kernel<<<blocks, 256, 0, stream>>>(
            t2bf, row_ptr, csr_src, dinv, b2, evidence, N_NODES);
    }
}

// Round 2
// 396.334 us; speedup vs baseline: 1.0361x; 1.0258x over previous
//
#include <hip/hip_runtime.h>

// EvidentialGNN: 2-layer GCN. evidence = softplus(gcn2(relu(gcn1(x)))).
// Outputs concatenated: (evidence[50000,64], h[50000,256]).
// R9: both GEMMs software-pipelined (double-buffered LDS; next-tile A-reg /
//     global_load_lds issued before current-tile MFMA). Generalized wave
//     tiling (2x2 waves, MRxNR frags) so GEMM2 runs BM=64,BN=64 -> 782 blocks
//     (was 196, <1 block/CU).

#define N_NODES 50000
#define IN_DIM 512
#define HID 256
#define NCLS 64

typedef unsigned short u16;
typedef unsigned int u32;
typedef __attribute__((ext_vector_type(8))) short short8;
typedef __attribute__((ext_vector_type(4))) float float4_t;

__device__ __forceinline__ float bf_lo(u32 v) {
    u32 u = v << 16; float f; __builtin_memcpy(&f, &u, 4); return f;
}
__device__ __forceinline__ float bf_hi(u32 v) {
    u32 u = v & 0xffff0000u; float f; __builtin_memcpy(&f, &u, 4); return f;
}
__device__ __forceinline__ u16 f2bf(float f) {   // RNE float->bf16
    u32 u; __builtin_memcpy(&u, &f, 4);
    return (u16)((u + 0x7fffu + ((u >> 16) & 1u)) >> 16);
}
__device__ __forceinline__ u32 pack2bf(float a, float b) {
    return (u32)f2bf(a) | ((u32)f2bf(b) << 16);
}
__device__ __forceinline__ void add8(float* acc, uint4 v) {
    acc[0] += bf_lo(v.x); acc[1] += bf_hi(v.x);
    acc[2] += bf_lo(v.y); acc[3] += bf_hi(v.y);
    acc[4] += bf_lo(v.z); acc[5] += bf_hi(v.z);
    acc[6] += bf_lo(v.w); acc[7] += bf_hi(v.w);
}
__device__ __forceinline__ void acc8(float* acc, uint4 v, float w) {
    acc[0] += w * bf_lo(v.x); acc[1] += w * bf_hi(v.x);
    acc[2] += w * bf_lo(v.y); acc[3] += w * bf_hi(v.y);
    acc[4] += w * bf_lo(v.z); acc[5] += w * bf_hi(v.z);
    acc[6] += w * bf_lo(v.w); acc[7] += w * bf_hi(v.w);
}

// ---------------- graph prep ----------------
__global__ void init_kernel(int* __restrict__ cnt, int* __restrict__ cursor, int n) {
    int i = blockIdx.x * blockDim.x + threadIdx.x;
    if (i < n) { cnt[i] = 0; cursor[i] = 0; }
}

__global__ void count_kernel(const int* __restrict__ dst, int* __restrict__ cnt, int E) {
    int e = blockIdx.x * blockDim.x + threadIdx.x;
    if (e < E) atomicAdd(&cnt[dst[e]], 1);
}

// s1: per-block reduce of cnt -> blocksum; fused dinv = rsqrt(cnt+1).
__global__ __launch_bounds__(256) void s1_kernel(const int* __restrict__ cnt,
                                                 int* __restrict__ blocksum,
                                                 float* __restrict__ dinv, int n) {
    int tid = threadIdx.x;
    int i = blockIdx.x * 256 + tid;
    int c = (i < n) ? cnt[i] : 0;
    if (i < n) dinv[i] = rsqrtf((float)(c + 1));  // +1 self-loop
    __shared__ int s[256];
    s[tid] = c;
    __syncthreads();
    for (int off = 128; off > 0; off >>= 1) {
        if (tid < off) s[tid] += s[tid + off];
        __syncthreads();
    }
    if (tid == 0) blocksum[blockIdx.x] = s[0];
}

// s3 (fused s2): every block scans the <=256 block sums in LDS to get its own
// offset, then does the block-local exclusive scan -> row_ptr[0..n].
__global__ __launch_bounds__(256) void s3_kernel(const int* __restrict__ cnt,
                                                 const int* __restrict__ blocksum,
                                                 int* __restrict__ row_ptr, int n, int nb) {
    __shared__ int bs[256];
    __shared__ int s[256];
    int tid = threadIdx.x;
    int v = (tid < nb) ? blocksum[tid] : 0;
    bs[tid] = v;
    __syncthreads();
    for (int off = 1; off < 256; off <<= 1) {
        int a = (tid >= off) ? bs[tid - off] : 0;
        __syncthreads();
        bs[tid] += a;
        __syncthreads();
    }
    int boff = (blockIdx.x == 0) ? 0 : bs[blockIdx.x - 1];
    int i = blockIdx.x * 256 + tid;
    int c = (i < n) ? cnt[i] : 0;
    s[tid] = c;
    __syncthreads();
    for (int off = 1; off < 256; off <<= 1) {
        int a = (tid >= off) ? s[tid - off] : 0;
        __syncthreads();
        s[tid] += a;
        __syncthreads();
    }
    if (i <= n) row_ptr[i] = boff + s[tid] - c;
}

__global__ void fill_kernel(const int* __restrict__ src, const int* __restrict__ dst,
                            const int* __restrict__ row_ptr, int* __restrict__ cursor,
                            int* __restrict__ csr_src, int E) {
    int e = blockIdx.x * blockDim.x + threadIdx.x;
    if (e >= E) return;
    int d = dst[e];
    int pos = row_ptr[d] + atomicAdd(&cursor[d], 1);
    csr_src[pos] = src[e];
}

// ---------------- casts ----------------
// Wt[n][k] = bf16(W[k][n]);  W is [K,N] row-major, Wt is [N,K] row-major.
__global__ __launch_bounds__(256) void tcast_kernel(const float* __restrict__ W,
                                                    u16* __restrict__ Wt, int K, int N) {
    int idx = blockIdx.x * 256 + threadIdx.x;
    if (idx >= K * N) return;
    int n = idx / K, k = idx - n * K;
    Wt[idx] = f2bf(W[k * N + n]);
}

// ---------------- bf16 MFMA GEMM (2-phase pipelined) ----------------
// C[M,N] = A[M,K] @ Bt[N,K]^T, fp32 accumulate, bf16 out.
// AF32: A is fp32, converted to bf16 in the A-staging (reg-stage + ds_write).
// SCALE: epilogue multiplies each output row by rowscale[row] (= dinv).
// 256 threads = 2x2 waves; per-wave (BM/2)x(BN/2) via MRxNR 16x16x32 MFMA.
// BK=32, double-buffered LDS: iteration t issues loads for t+1 into buf^1,
// computes buf, writes A-regs late (latency hidden under MFMA), one barrier.
template <int BM, int BN, int K, int N, bool AF32, bool SCALE>
__global__ __launch_bounds__(256) void mfma_gemm_kernel(const void* __restrict__ Ain,
                                                        const u16* __restrict__ Bt,
                                                        u16* __restrict__ C, int M,
                                                        const float* __restrict__ rowscale) {
    constexpr int WROWS = 2, WCOLS = 2;
    constexpr int WMR = BM / WROWS;      // rows per wave
    constexpr int WNR = BN / WCOLS;      // cols per wave
    constexpr int MR = WMR / 16;         // A-frag repeat
    constexpr int NR = WNR / 16;         // B-frag repeat
    constexpr int AI = BM / 64;          // A staging iters (256 thr x 8 u16 = 64 rows x 32 k)
    constexpr int BI = BN / 64;          // B staging iters
    constexpr int LDSA = BM * 32;        // u16 per buffer
    constexpr int LDSB = BN * 32;
    constexpr int LDST = LDSA + LDSB;
    constexpr int NT = K / 32;
    static_assert(MR * 16 * WROWS == BM && NR * 16 * WCOLS == BN, "tiling");
    __shared__ u16 lds[2 * LDST];

    const int tid = threadIdx.x;
    const int wave = tid >> 6, lane = tid & 63;
    const int wm = wave / WCOLS, wn = wave % WCOLS;
    const int quad = lane >> 4, l15 = lane & 15;
    const int row0 = blockIdx.y * BM;
    const int col0 = blockIdx.x * BN;

    const float* Af = (const float*)Ain;
    const u16* Abf = (const u16*)Ain;

    // clamped global A rows for the staging lanes (computed once)
    int gra[AI];
#pragma unroll
    for (int i = 0; i < AI; i++) {
        int gr = row0 + ((tid + i * 256) >> 2);
        gra[i] = gr < M ? gr : M - 1;
    }

    float4 pa[AI][2];  // AF32: in-flight A fp32 for the next k-step

    auto loadA = [&](int k0) {  // AF32 only: issue global loads into pa
#pragma unroll
        for (int i = 0; i < AI; i++) {
            int c = tid + i * 256;
            const float* gp = Af + (long)gra[i] * K + k0 + (c & 3) * 8;
            pa[i][0] = ((const float4*)gp)[0];
            pa[i][1] = ((const float4*)gp)[1];
        }
    };
    auto writeA = [&](u16* buf) {  // AF32 only: convert + ds_write (waits pa)
#pragma unroll
        for (int i = 0; i < AI; i++) {
            int c = tid + i * 256;
            uint4 o;
            o.x = pack2bf(pa[i][0].x, pa[i][0].y);
            o.y = pack2bf(pa[i][0].z, pa[i][0].w);
            o.z = pack2bf(pa[i][1].x, pa[i][1].y);
            o.w = pack2bf(pa[i][1].z, pa[i][1].w);
            *(uint4*)(buf + c * 8) = o;
        }
    };
    auto stageA_lds = [&](int k0, u16* buf) {  // bf16 A via async global->LDS
#pragma unroll
        for (int i = 0; i < AI; i++) {
            int c = tid + i * 256;
            const u16* gp = Abf + (long)gra[i] * K + k0 + (c & 3) * 8;
            __builtin_amdgcn_global_load_lds((const __attribute__((address_space(1))) u32*)gp,
                                             (__attribute__((address_space(3))) u32*)(buf + c * 8),
                                             16, 0, 0);
        }
    };
    auto stageB = [&](int k0, u16* buf) {
#pragma unroll
        for (int i = 0; i < BI; i++) {
            int c = tid + i * 256;
            int r = c >> 2;
            const u16* gp = Bt + (long)(col0 + r) * K + k0 + (c & 3) * 8;
            __builtin_amdgcn_global_load_lds((const __attribute__((address_space(1))) u32*)gp,
                                             (__attribute__((address_space(3))) u32*)(buf + c * 8),
                                             16, 0, 0);
        }
    };

    float4_t acc[MR][NR];
#pragma unroll
    for (int mi = 0; mi < MR; mi++)
#pragma unroll
        for (int ni = 0; ni < NR; ni++) {
            float4_t z = {0.f, 0.f, 0.f, 0.f};
            acc[mi][ni] = z;
        }

    // prologue: stage t=0 into buffer 0
    if constexpr (AF32) {
        loadA(0);
        writeA(lds);
    } else {
        stageA_lds(0, lds);
    }
    stageB(0, lds + LDSA);
    __syncthreads();

    for (int t = 0; t < NT; t++) {
        u16* cur = lds + (t & 1) * LDST;
        u16* nxt = lds + ((t + 1) & 1) * LDST;
        const bool pre = (t + 1) < NT;
        if (pre) {  // issue next-tile loads first (latency hides under MFMA)
            if constexpr (AF32) loadA((t + 1) * 32);
            else stageA_lds((t + 1) * 32, nxt);
            stageB((t + 1) * 32, nxt + LDSA);
        }

        short8 af[MR], bfr[NR];
#pragma unroll
        for (int mi = 0; mi < MR; mi++)
            af[mi] = *(const short8*)(cur + (wm * WMR + mi * 16 + l15) * 32 + quad * 8);
#pragma unroll
        for (int ni = 0; ni < NR; ni++)
            bfr[ni] = *(const short8*)(cur + LDSA + (wn * WNR + ni * 16 + l15) * 32 + quad * 8);
#pragma unroll
        for (int mi = 0; mi < MR; mi++)
#pragma unroll
            for (int ni = 0; ni < NR; ni++)
                acc[mi][ni] = __builtin_amdgcn_mfma_f32_16x16x32_bf16(af[mi], bfr[ni],
                                                                      acc[mi][ni], 0, 0, 0);
        if (pre) {
            if constexpr (AF32) writeA(nxt);  // vmcnt wait lands after MFMA cluster
        }
        __syncthreads();
    }

#pragma unroll
    for (int mi = 0; mi < MR; mi++) {
#pragma unroll
        for (int r = 0; r < 4; r++) {
            int row = row0 + wm * WMR + mi * 16 + quad * 4 + r;
            if (row < M) {
                float sc = 1.f;
                if constexpr (SCALE) sc = rowscale[row];
#pragma unroll
                for (int ni = 0; ni < NR; ni++) {
                    int col = col0 + wn * WNR + ni * 16 + l15;
                    C[(long)row * N + col] = f2bf(acc[mi][ni][r] * sc);
                }
            }
        }
    }
}

// ---------------- agg1: wide rows (FEAT=256), one node per wave ----------------
// Rows in t are PRE-SCALED by dinv[src] (GEMM epilogue), so the inner loop is a
// pure row-sum: out = dinv[d]*(sum + self) + b.  32 lanes cover a 512B row with
// uint4; 2 edge groups; tiered unroll 16/8/2.
__global__ __launch_bounds__(256) void agg_wide_kernel(const u16* __restrict__ t,
                                                       const int* __restrict__ row_ptr,
                                                       const int* __restrict__ csr_src,
                                                       const float* __restrict__ dinv,
                                                       const float* __restrict__ bias,
                                                       float* __restrict__ out_f,
                                                       u16* __restrict__ out_bf, int n) {
    constexpr int FEAT = 256;
    int node = (blockIdx.x * blockDim.x + threadIdx.x) >> 6;
    int lane = threadIdx.x & 63;
    if (node >= n) return;
    const int g = lane >> 5;       // edge group 0..1
    const int r = lane & 31;       // lane within row
    float acc[8] = {};
    const int beg = row_ptr[node], end = row_ptr[node + 1];
    int e = beg;
    for (; e + 16 <= end; e += 16) {   // 8 edges per group, 16 chains in flight
        int s[8]; uint4 v[8];
#pragma unroll
        for (int u = 0; u < 8; u++) s[u] = csr_src[e + u * 2 + g];
#pragma unroll
        for (int u = 0; u < 8; u++) v[u] = *(const uint4*)(t + (long)s[u] * FEAT + r * 8);
#pragma unroll
        for (int u = 0; u < 8; u++) add8(acc, v[u]);
    }
    for (; e + 8 <= end; e += 8) {
        int s[4]; uint4 v[4];
#pragma unroll
        for (int u = 0; u < 4; u++) s[u] = csr_src[e + u * 2 + g];
#pragma unroll
        for (int u = 0; u < 4; u++) v[u] = *(const uint4*)(t + (long)s[u] * FEAT + r * 8);
#pragma unroll
        for (int u = 0; u < 4; u++) add8(acc, v[u]);
    }
    for (; e < end; e += 2) {
        int ee = e + g;
        if (ee < end) {
            int s = csr_src[ee];
            uint4 v = *(const uint4*)(t + (long)s * FEAT + r * 8);
            add8(acc, v);
        }
    }
#pragma unroll
    for (int j = 0; j < 8; j++) acc[j] += __shfl_xor(acc[j], 32, 64);

    if (lane < 32) {
        const float di = dinv[node];
        uint4 sv = *(const uint4*)(t + (long)node * FEAT + lane * 8);
        float self[8] = {bf_lo(sv.x), bf_hi(sv.x), bf_lo(sv.y), bf_hi(sv.y),
                         bf_lo(sv.z), bf_hi(sv.z), bf_lo(sv.w), bf_hi(sv.w)};
        float4 b0 = *(const float4*)(bias + lane * 8);
        float4 b1 = *(const float4*)(bias + lane * 8 + 4);
        float bb[8] = {b0.x, b0.y, b0.z, b0.w, b1.x, b1.y, b1.z, b1.w};
        float rv[8];
#pragma unroll
        for (int j = 0; j < 8; j++)
            rv[j] = fmaxf(di * (acc[j] + self[j]) + bb[j], 0.f);  // relu
        long base = (long)node * FEAT + lane * 8;
        *(float4*)(out_f + base) = make_float4(rv[0], rv[1], rv[2], rv[3]);
        *(float4*)(out_f + base + 4) = make_float4(rv[4], rv[5], rv[6], rv[7]);
        uint4 o;
        o.x = (u32)f2bf(rv[0]) | ((u32)f2bf(rv[1]) << 16);
        o.y = (u32)f2bf(rv[2]) | ((u32)f2bf(rv[3]) << 16);
        o.z = (u32)f2bf(rv[4]) | ((u32)f2bf(rv[5]) << 16);
        o.w = (u32)f2bf(rv[6]) | ((u32)f2bf(rv[7]) << 16);
        *(uint4*)(out_bf + base) = o;
    }
}

// ---------------- agg2: narrow rows (FEAT=64), 8 nodes per wave ----------------
// Rows in t are PRE-SCALED by dinv[src].  8 lanes x 16B cover a 128B row; each
// 8-lane group owns one node; 4 edges in flight per group (w=1/0 masks tails).
__global__ __launch_bounds__(256) void agg_n8_kernel(const u16* __restrict__ t,
                                                     const int* __restrict__ row_ptr,
                                                     const int* __restrict__ csr_src,
                                                     const float* __restrict__ dinv,
                                                     const float* __restrict__ bias,
                                                     float* __restrict__ out_f, int n) {
    constexpr int FEAT = 64;
    const int wid = (blockIdx.x * blockDim.x + threadIdx.x) >> 6;
    const int lane = threadIdx.x & 63;
    const int g = lane >> 3;   // node group 0..7
    const int r = lane & 7;    // lane within row
    const int node = wid * 8 + g;
    const bool valid = node < n;
    const int nd = valid ? node : (n - 1);
    const int beg = row_ptr[nd];
    const int deg = valid ? (row_ptr[nd + 1] - beg) : 0;
    float acc[8] = {};
    for (int e = 0;; e += 4) {
        if (!__any(e < deg)) break;
        int s[4]; float w[4]; uint4 v[4];
#pragma unroll
        for (int u = 0; u < 4; u++) {
            bool a = (e + u) < deg;
            s[u] = a ? csr_src[beg + e + u] : 0;
            w[u] = a ? 1.f : 0.f;
        }
#pragma unroll
        for (int u = 0; u < 4; u++) v[u] = *(const uint4*)(t + (long)s[u] * FEAT + r * 8);
#pragma unroll
        for (int u = 0; u < 4; u++) acc8(acc, v[u], w[u]);  // w=0 kills garbage rows
    }
    const float di = dinv[nd];
    uint4 sv = *(const uint4*)(t + (long)nd * FEAT + r * 8);
    float self[8] = {bf_lo(sv.x), bf_hi(sv.x), bf_lo(sv.y), bf_hi(sv.y),
                     bf_lo(sv.z), bf_hi(sv.z), bf_lo(sv.w), bf_hi(sv.w)};
    float4 b0 = *(const float4*)(bias + r * 8);
    float4 b1 = *(const float4*)(bias + r * 8 + 4);
    float bb[8] = {b0.x, b0.y, b0.z, b0.w, b1.x, b1.y, b1.z, b1.w};
    float rv[8];
#pragma unroll
    for (int j = 0; j < 8; j++) {
        float v = di * (acc[j] + self[j]) + bb[j];
        // fast softplus: max(v,0) + ln(1+exp(-|v|)) via v_exp/v_log
        rv[j] = fmaxf(v, 0.f) + __logf(1.f + __expf(-fabsf(v)));
    }
    if (valid) {
        long base = (long)nd * FEAT + r * 8;
        *(float4*)(out_f + base) = make_float4(rv[0], rv[1], rv[2], rv[3]);
        *(float4*)(out_f + base + 4) = make_float4(rv[4], rv[5], rv[6], rv[7]);
    }
}

extern "C" void kernel_launch(void* const* d_in, const int* in_sizes, int n_in,
                              void* d_out, int out_size, void* d_ws, size_t ws_size,
                              hipStream_t stream) {
    const float* x  = (const float*)d_in[0];
    const int*   ei = (const int*)d_in[1];
    const float* W1 = (const float*)d_in[2];
    const float* b1 = (const float*)d_in[3];
    const float* W2 = (const float*)d_in[4];
    const float* b2 = (const float*)d_in[5];

    float* evidence = (float*)d_out;                        // [50000, 64]
    float* h        = (float*)d_out + (long)N_NODES * NCLS; // [50000, 256]

    const int E = in_sizes[1] / 2;
    const int* src = ei;
    const int* dst = ei + E;

    const int NB = (N_NODES + 255) / 256;  // 196 scan blocks

    // workspace carve-up (16B-aligned regions)
    char* w = (char*)d_ws;
    int*   cnt      = (int*)w;  w += 50048 * 4;
    int*   cursor   = (int*)w;  w += 50048 * 4;
    int*   row_ptr  = (int*)w;  w += 50064 * 4;
    float* dinv     = (float*)w; w += 50048 * 4;
    int*   blocksum = (int*)w;  w += 256 * 4;
    int*   csr_src  = (int*)w;  w += 800000 * 4;
    u16*   hbf      = (u16*)w;  w += (long)N_NODES * IN_DIM * 2;  // h bf16 (only HID used)
    u16*   w1t      = (u16*)w;  w += IN_DIM * HID * 2;
    u16*   w2t      = (u16*)w;  w += HID * NCLS * 2;
    u16*   t1bf     = (u16*)w;  w += (long)N_NODES * HID * 2;     // reused as t2_bf
    u16*   t2bf     = t1bf;

    // graph prep
    init_kernel<<<NB, 256, 0, stream>>>(cnt, cursor, N_NODES);
    count_kernel<<<(E + 255) / 256, 256, 0, stream>>>(dst, cnt, E);
    s1_kernel<<<NB, 256, 0, stream>>>(cnt, blocksum, dinv, N_NODES);
    s3_kernel<<<NB, 256, 0, stream>>>(cnt, blocksum, row_ptr, N_NODES, NB);
    fill_kernel<<<(E + 255) / 256, 256, 0, stream>>>(src, dst, row_ptr, cursor, csr_src, E);

    // weight casts
    tcast_kernel<<<(IN_DIM * HID + 255) / 256, 256, 0, stream>>>(W1, w1t, IN_DIM, HID);
    tcast_kernel<<<(HID * NCLS + 255) / 256, 256, 0, stream>>>(W2, w2t, HID, NCLS);

    // layer 1: t1 = dinv .* (x @ W1)  (fp32 A fused-cast, scaled epilogue);
    //          h = relu(dinv[d]*(sum t1[s] + t1[d]) + b1), also h_bf
    {
        dim3 grid(HID / 128, (N_NODES + 127) / 128);
        mfma_gemm_kernel<128, 128, IN_DIM, HID, true, true>
            <<<grid, 256, 0, stream>>>(x, w1t, t1bf, N_NODES, dinv);
    }
    agg_wide_kernel<<<(N_NODES * 64 + 255) / 256, 256, 0, stream>>>(
        t1bf, row_ptr, csr_src, dinv, b1, h, hbf, N_NODES);

    // layer 2: t2 = dinv .* (h @ W2); evidence = softplus(dinv[d]*(sum+self) + b2)
    {
        dim3 grid(NCLS / 64, (N_NODES + 63) / 64);
        mfma_gemm_kernel<64, 64, HID, NCLS, false, true>
            <<<grid, 256, 0, stream>>>(hbf, w2t, t2bf, N_NODES, dinv);
    }
    {
        int waves = (N_NODES + 7) / 8;                 // 6250 waves
        int blocks = (waves + 3) / 4;                  // 4 waves per block
        agg_n8_kernel<<<blocks, 256, 0, stream>>>(
            t2bf, row_ptr, csr_src, dinv, b2, evidence, N_NODES);
    }
}